// Round 5
// baseline (309.564 us; speedup 1.0000x reference)
//
#include <hip/hip_runtime.h>

#define NTOT 196608
#define BAGS 4096
#define H 230
#define H3 690
#define NC 53

// One-instruction cross-lane reduce step: ds_swizzle BitMode xor patterns.
// (xor<<10)|(or<<5)|and, and=0x1F. Operates within 32-lane halves (enough:
// we only use xor 1,2,4 per-row, and xor 1..16 in the z-reduce).
#define SWZ_ADD(v, pat) \
    ((v) + __int_as_float(__builtin_amdgcn_ds_swizzle(__float_as_int(v), (pat))))

// tanh(x) = 1 - 2/(exp(2x)+1), v_rcp instead of precise division.
__device__ __forceinline__ float fast_tanh(float x) {
    float e = __expf(2.f * x);
    float r = __builtin_amdgcn_rcpf(e + 1.f);
    return fmaf(-2.f, r, 1.f);
}

// ---------------------------------------------------------------------------
// Kernel 0: per-class table (53 classes). Unchanged (≈2 µs).
// cls[0*NC+c]=logit const k=0, cls[1*NC+c]=k=1, cls[2*NC+c]=vsm0, cls[3*NC+c]=vsm1
// ---------------------------------------------------------------------------
__global__ void class_table_kernel(const float* __restrict__ rel_emb0,
                                   const float* __restrict__ rel_emb1,
                                   const float* __restrict__ att_w0,
                                   const float* __restrict__ att_w1,
                                   const float* __restrict__ w_s,
                                   const float* __restrict__ b_s,
                                   const int* __restrict__ relation_levels,
                                   float* __restrict__ cls)
{
    int c = blockIdx.x;
    int lane = threadIdx.x;  // 64 threads
    int l0 = relation_levels[c * 2 + 0];
    int l1 = relation_levels[c * 2 + 1];
    float a00 = 0.f, a01 = 0.f, a10 = 0.f, a11 = 0.f;
    for (int j = lane; j < H; j += 64) {
        float t0 = fast_tanh(rel_emb0[l0 * H + j]);
        float t1 = fast_tanh(rel_emb1[l1 * H + j]);
        a00 += w_s[0 * H3 + H + j] * t0;
        a01 += w_s[0 * H3 + 2 * H + j] * t1;
        a10 += w_s[1 * H3 + H + j] * t0;
        a11 += w_s[1 * H3 + 2 * H + j] * t1;
    }
    for (int m = 32; m; m >>= 1) {
        a00 += __shfl_xor(a00, m);
        a01 += __shfl_xor(a01, m);
        a10 += __shfl_xor(a10, m);
        a11 += __shfl_xor(a11, m);
    }
    if (lane == 0) {
        cls[0 * NC + c] = a00 + a01 + b_s[0];
        cls[1 * NC + c] = a10 + a11 + b_s[1];
        float v0 = att_w0[l0], v1 = att_w1[l1];
        float mx = fmaxf(v0, v1);
        float e0 = __expf(v0 - mx), e1 = __expf(v1 - mx);
        float rz = __builtin_amdgcn_rcpf(e0 + e1);
        cls[2 * NC + c] = e0 * rz;
        cls[3 * NC + c] = e1 * rz;
    }
}

// ---------------------------------------------------------------------------
// Kernel 1. R4 diagnosis: VALU-issue = ~5100 cy/wave vs ~1500 useful —
// instruction bloat (vector 64b addr math, 6-step ds_bpermute butterflies,
// 48 global cls loads on the critical path). This version cuts the stream:
//  * scalar (readfirstlane) row offsets -> saddr-form loads, per-lane voff
//    computed once
//  * reduce = 3 ds_swizzle (xor 1/2/4, immediate pattern, 1 op each) to
//    8-lane partials -> leaders write float2 -> 48-thread LDS stage does
//    final 8-way sum + exp -> e broadcast via LDS. No barriers added beyond
//    2 per chunk (1 chunk for cnt=48).
//  * cls table preloaded to LDS (212 floats) once per block
//  * rb loads clamped (min(lane,50), always in-bounds) -> no exec masks;
//    garbage lanes are multiplied by pre-zeroed weights and never stored.
// Rows live in registers (48 VGPR); (256,6) => 85-reg cap vs ~78 demand.
// WRITE_SIZE is the spill tripwire: must stay ~1 MB.
// ---------------------------------------------------------------------------
__global__ __launch_bounds__(256, 6) void bag_kernel(
    const float* __restrict__ x,
    const float* __restrict__ w_s,
    const float* __restrict__ disc,
    const float* __restrict__ bias,
    const int* __restrict__ label_index,
    const int* __restrict__ scope,
    const float* __restrict__ cls,
    float* __restrict__ out)
{
    // ldsA: dp partials [48][9] float2 = 864 floats, overlaid later by
    // part[4][464] (1856 floats) + t01 (464 floats) = 2320 floats total.
    __shared__ __align__(16) float ldsA[2320];
    __shared__ __align__(16) float clsL[4 * NC];   // 212
    __shared__ __align__(8)  float2 eL[48];
    __shared__ float zsL[2];

    int b = blockIdx.x;
    int tid = threadIdx.x;
    int wave = tid >> 6;
    int lane = tid & 63;

    if (tid < 4 * NC) clsL[tid] = cls[tid];

    int sstart = __builtin_amdgcn_readfirstlane(scope[b]);
    int cnt    = __builtin_amdgcn_readfirstlane(scope[b + 1]) - sstart;
    int swave  = __builtin_amdgcn_readfirstlane(wave);

    // Per-lane float2 indices within a row, computed once.
    int li = (lane < 51) ? lane : 50;      // clamp: elems 228/229, in-bounds

    // w_s slices in registers (zero past H for lanes >= 51).
    const float2* w0p = (const float2*)w_s;          // 115 float2
    const float2* w1p = (const float2*)(w_s + H3);
    float2 w0a = w0p[lane], w1a = w1p[lane];
    float2 w0b = make_float2(0.f, 0.f), w1b = make_float2(0.f, 0.f);
    if (lane < 51) { w0b = w0p[64 + lane]; w1b = w1p[64 + lane]; }

    float2* dpF2 = (float2*)ldsA;          // [48][9] float2, pad 1 -> low conflict

    float2 acc0a = make_float2(0.f, 0.f), acc0b = make_float2(0.f, 0.f);
    float2 acc1a = make_float2(0.f, 0.f), acc1b = make_float2(0.f, 0.f);
    float z0t = 0.f, z1t = 0.f, sv0t = 0.f, sv1t = 0.f;

    for (int cb = 0; cb < cnt; cb += 48) {
        int rows = cnt - cb; if (rows > 48) rows = 48;

        float2 ra[12], rb[12];
        // ---- dot phase: per row: 2 saddr loads, 4 tanh, 8 fma, 3 swizzle
        // steps per logit, 1 leader ds_write_b64. All rows independent.
#pragma unroll
        for (int t = 0; t < 12; ++t) {
            int r = swave + 4 * t;                 // scalar, local row id
            if (r < rows) {
                int roff = (sstart + cb + r) * H;  // scalar element offset
                const float2* rp = (const float2*)(x + roff);
                float2 a  = rp[lane];
                float2 bb = rp[64 + li];
                ra[t] = a; rb[t] = bb;
                float t0 = fast_tanh(a.x),  t1 = fast_tanh(a.y);
                float t2 = fast_tanh(bb.x), t3 = fast_tanh(bb.y);
                float d0 = w0a.x * t0 + w0a.y * t1 + w0b.x * t2 + w0b.y * t3;
                float d1 = w1a.x * t0 + w1a.y * t1 + w1b.x * t2 + w1b.y * t3;
                d0 = SWZ_ADD(d0, 0x041F);  // xor 1
                d0 = SWZ_ADD(d0, 0x081F);  // xor 2
                d0 = SWZ_ADD(d0, 0x101F);  // xor 4 -> 8-lane group sums
                d1 = SWZ_ADD(d1, 0x041F);
                d1 = SWZ_ADD(d1, 0x081F);
                d1 = SWZ_ADD(d1, 0x101F);
                if ((lane & 7) == 0)
                    dpF2[r * 9 + (lane >> 3)] = make_float2(d0, d1);
            }
        }
        __syncthreads();

        // ---- reduce+exp stage: 48 threads (wave 0), one row each:
        // 8 float2 LDS reads, 16 adds, 2 exp, 1 float2 write.
        if (tid < 64) {
            int r = tid;
            float e0 = 0.f, e1 = 0.f, sp0 = 0.f, sp1 = 0.f;
            if (r < rows) {
                int c = label_index[sstart + cb + r];
                float d0 = 0.f, d1 = 0.f;
#pragma unroll
                for (int p = 0; p < 8; ++p) {
                    float2 v = dpF2[r * 9 + p];
                    d0 += v.x; d1 += v.y;
                }
                e0 = __expf(d0 + clsL[c]);
                e1 = __expf(d1 + clsL[NC + c]);
                sp0 = clsL[2 * NC + c];
                sp1 = clsL[3 * NC + c];
                eL[r] = make_float2(e0, e1);
            }
            z0t += e0; z1t += e1; sv0t += sp0; sv1t += sp1;
        }
        __syncthreads();

        // ---- accumulate: e broadcast from LDS (uniform addr), 8 fma/row.
#pragma unroll
        for (int t = 0; t < 12; ++t) {
            int r = swave + 4 * t;
            if (r < rows) {
                float2 e = eL[r];
                acc0a.x = fmaf(e.x, ra[t].x, acc0a.x);
                acc0a.y = fmaf(e.x, ra[t].y, acc0a.y);
                acc0b.x = fmaf(e.x, rb[t].x, acc0b.x);
                acc0b.y = fmaf(e.x, rb[t].y, acc0b.y);
                acc1a.x = fmaf(e.y, ra[t].x, acc1a.x);
                acc1a.y = fmaf(e.y, ra[t].y, acc1a.y);
                acc1b.x = fmaf(e.y, rb[t].x, acc1b.x);
                acc1b.y = fmaf(e.y, rb[t].y, acc1b.y);
            }
        }
    }

    // ---- z / sv totals: wave 0 holds per-lane partials (lane = row id).
    if (tid < 64) {
        z0t  = SWZ_ADD(z0t,  0x041F); z0t  = SWZ_ADD(z0t,  0x081F);
        z0t  = SWZ_ADD(z0t,  0x101F); z0t  = SWZ_ADD(z0t,  0x201F);
        z0t  = SWZ_ADD(z0t,  0x401F); z0t  += __shfl_xor(z0t, 32);
        z1t  = SWZ_ADD(z1t,  0x041F); z1t  = SWZ_ADD(z1t,  0x081F);
        z1t  = SWZ_ADD(z1t,  0x101F); z1t  = SWZ_ADD(z1t,  0x201F);
        z1t  = SWZ_ADD(z1t,  0x401F); z1t  += __shfl_xor(z1t, 32);
        sv0t = SWZ_ADD(sv0t, 0x041F); sv0t = SWZ_ADD(sv0t, 0x081F);
        sv0t = SWZ_ADD(sv0t, 0x101F); sv0t = SWZ_ADD(sv0t, 0x201F);
        sv0t = SWZ_ADD(sv0t, 0x401F); sv0t += __shfl_xor(sv0t, 32);
        sv1t = SWZ_ADD(sv1t, 0x041F); sv1t = SWZ_ADD(sv1t, 0x081F);
        sv1t = SWZ_ADD(sv1t, 0x101F); sv1t = SWZ_ADD(sv1t, 0x201F);
        sv1t = SWZ_ADD(sv1t, 0x401F); sv1t += __shfl_xor(sv1t, 32);
        if (lane == 0) {
            float rc = __builtin_amdgcn_rcpf((float)cnt);
            zsL[0] = sv0t * rc * __builtin_amdgcn_rcpf(z0t);
            zsL[1] = sv1t * rc * __builtin_amdgcn_rcpf(z1t);
        }
    }

    // ---- Cross-wave merge: part[4][464] overlays dpF2 (last dp read was
    // before the final chunk's second barrier).
    float2* pw = (float2*)(ldsA + wave * 464);
    pw[lane]       = acc0a;              // floats [0,128)
    pw[115 + lane] = acc1a;              // floats [230,358)
    if (lane < 51) {
        pw[64 + lane]       = acc0b;     // floats [128,230)
        pw[115 + 64 + lane] = acc1b;     // floats [358,460)
    }
    __syncthreads();

    float s0 = zsL[0], s1 = zsL[1];
    float* t01 = ldsA + 1856;
    for (int t = tid; t < 2 * H; t += 256) {
        float s = ldsA[t] + ldsA[464 + t] + ldsA[928 + t] + ldsA[1392 + t];
        t01[t] = s * (t < H ? s0 : s1);
    }
    __syncthreads();

    // ---- Output projection, float4 both sides. 4 threads per class.
    int q = tid & 3;
    int c = tid >> 2;
    if (c < NC) {
        const float4* drow4 = (const float4*)(disc + c * (2 * H)); // 115 float4
        const float4* t4 = (const float4*)t01;
        float acc = 0.f;
        for (int k = q; k < 115; k += 4) {
            float4 dv = drow4[k];
            float4 tv = t4[k];
            acc += dv.x * tv.x + dv.y * tv.y + dv.z * tv.z + dv.w * tv.w;
        }
        acc += __shfl_down(acc, 2, 4);
        acc += __shfl_down(acc, 1, 4);
        if (q == 0) out[b * NC + c] = acc + bias[c];
    }
}

extern "C" void kernel_launch(void* const* d_in, const int* in_sizes, int n_in,
                              void* d_out, int out_size, void* d_ws, size_t ws_size,
                              hipStream_t stream) {
    const float* x               = (const float*)d_in[0];
    const float* rel_emb0        = (const float*)d_in[1];
    const float* rel_emb1        = (const float*)d_in[2];
    const float* att_w0          = (const float*)d_in[3];
    const float* att_w1          = (const float*)d_in[4];
    const float* w_s             = (const float*)d_in[5];
    const float* b_s             = (const float*)d_in[6];
    const float* disc            = (const float*)d_in[7];
    const float* bias            = (const float*)d_in[8];
    const int*   label_index     = (const int*)d_in[9];
    const int*   relation_levels = (const int*)d_in[10];
    const int*   scope           = (const int*)d_in[11];
    float* out = (float*)d_out;
    float* cls = (float*)d_ws;   // 4*NC floats

    class_table_kernel<<<NC, 64, 0, stream>>>(rel_emb0, rel_emb1, att_w0, att_w1,
                                              w_s, b_s, relation_levels, cls);
    bag_kernel<<<BAGS, 256, 0, stream>>>(x, w_s, disc, bias, label_index, scope,
                                         cls, out);
}

// Round 6
// 298.894 us; speedup vs baseline: 1.0357x; 1.0357x over previous
//
#include <hip/hip_runtime.h>

#define NTOT 196608
#define BAGS 4096
#define H 230
#define H3 690
#define NC 53

// tanh(x) = 1 - 2/(exp(2x)+1), v_rcp instead of precise division.
// Saturates correctly at +/-1 for large |x|.
__device__ __forceinline__ float fast_tanh(float x) {
    float e = __expf(2.f * x);
    float r = __builtin_amdgcn_rcpf(e + 1.f);
    return fmaf(-2.f, r, 1.f);
}

// ---------------------------------------------------------------------------
// Kernel 0: per-class table (53 classes). Unchanged.
// cls[0*NC+c]=logit const k=0, cls[1*NC+c]=k=1, cls[2*NC+c]=vsm0, cls[3*NC+c]=vsm1
// ---------------------------------------------------------------------------
__global__ void class_table_kernel(const float* __restrict__ rel_emb0,
                                   const float* __restrict__ rel_emb1,
                                   const float* __restrict__ att_w0,
                                   const float* __restrict__ att_w1,
                                   const float* __restrict__ w_s,
                                   const float* __restrict__ b_s,
                                   const int* __restrict__ relation_levels,
                                   float* __restrict__ cls)
{
    int c = blockIdx.x;
    int lane = threadIdx.x;  // 64 threads
    int l0 = relation_levels[c * 2 + 0];
    int l1 = relation_levels[c * 2 + 1];
    float a00 = 0.f, a01 = 0.f, a10 = 0.f, a11 = 0.f;
    for (int j = lane; j < H; j += 64) {
        float t0 = fast_tanh(rel_emb0[l0 * H + j]);
        float t1 = fast_tanh(rel_emb1[l1 * H + j]);
        a00 += w_s[0 * H3 + H + j] * t0;
        a01 += w_s[0 * H3 + 2 * H + j] * t1;
        a10 += w_s[1 * H3 + H + j] * t0;
        a11 += w_s[1 * H3 + 2 * H + j] * t1;
    }
    for (int m = 32; m; m >>= 1) {
        a00 += __shfl_xor(a00, m);
        a01 += __shfl_xor(a01, m);
        a10 += __shfl_xor(a10, m);
        a11 += __shfl_xor(a11, m);
    }
    if (lane == 0) {
        cls[0 * NC + c] = a00 + a01 + b_s[0];
        cls[1 * NC + c] = a10 + a11 + b_s[1];
        float v0 = att_w0[l0], v1 = att_w1[l1];
        float mx = fmaxf(v0, v1);
        float e0 = __expf(v0 - mx), e1 = __expf(v1 - mx);
        float rz = __builtin_amdgcn_rcpf(e0 + e1);
        cls[2 * NC + c] = e0 * rz;
        cls[3 * NC + c] = e1 * rz;
    }
}

// ---------------------------------------------------------------------------
// Kernel 1: one block per bag, SINGLE pass over x.
// Evidence across R0-R5: kernel is LATENCY-bound (VALUBusy<=32%, HBM<=18%
// in every variant); the only fast config was R0's plain rolled loop at
// (256,8) max occupancy (32 waves/CU). Structures that bought ILP with
// registers/LDS at lower occupancy all lost (R3 61%->120us, R4 40%->105us,
// R5 61%->108us). This version = R0's shape + max occupancy + exactly
// depth-1 rotating prefetch (rolled, #pragma unroll 1 -> short lifetimes,
// ~55 VGPR demand under the 64 cap) + scalar memory path (readfirstlane
// row offset -> saddr loads; readfirstlane class -> cls via s_load).
// Tripwires: VGPR must stay ~55-64, WRITE_SIZE ~1 MB (else scratch).
// ---------------------------------------------------------------------------
__global__ __launch_bounds__(256, 8) void bag_kernel(
    const float* __restrict__ x,
    const float* __restrict__ w_s,
    const float* __restrict__ disc,
    const float* __restrict__ bias,
    const int* __restrict__ label_index,
    const int* __restrict__ scope,
    const float* __restrict__ cls,
    float* __restrict__ out)
{
    __shared__ __align__(16) float part[4][464];   // per-wave weighted-sum partials
    __shared__ float zs[4][4];                     // per-wave z0,z1,sv0,sv1
    __shared__ __align__(16) float t01[464];       // tower (t0 | t1)

    int b = blockIdx.x;
    int tid = threadIdx.x;
    int wave = tid >> 6;
    int lane = tid & 63;

    int start = __builtin_amdgcn_readfirstlane(scope[b]);
    int cnt   = __builtin_amdgcn_readfirstlane(scope[b + 1]) - start;
    int swave = __builtin_amdgcn_readfirstlane(wave);

    // w_s slices hoisted to registers as float2 (zero past H).
    const float2* w0p = (const float2*)w_s;          // 115 float2
    const float2* w1p = (const float2*)(w_s + H3);   // 690 % 2 == 0, aligned
    float2 w0a = w0p[lane];
    float2 w1a = w1p[lane];
    float2 w0b = make_float2(0.f, 0.f), w1b = make_float2(0.f, 0.f);
    if (lane < 51) { w0b = w0p[64 + lane]; w1b = w1p[64 + lane]; }

    float2 acc0a = make_float2(0.f, 0.f), acc0b = make_float2(0.f, 0.f);
    float2 acc1a = make_float2(0.f, 0.f), acc1b = make_float2(0.f, 0.f);
    float z0 = 0.f, z1 = 0.f, sv0 = 0.f, sv1 = 0.f;

    if (cnt == 48) {
        // ---- depth-1 rotating software pipeline, rolled (12 trips).
        // Current row state: a, bb, k0,k1 (logit consts), p0,p1 (vsm).
        int roff0 = (start + swave) * H;             // scalar
        const float2* rp0 = (const float2*)(x + roff0);
        float2 a  = rp0[lane];
        float2 bb = (lane < 51) ? rp0[64 + lane] : make_float2(0.f, 0.f);
        int c0 = __builtin_amdgcn_readfirstlane(label_index[start + swave]);
        float k0 = cls[c0],        k1 = cls[NC + c0];
        float p0 = cls[2*NC + c0], p1 = cls[3*NC + c0];

#pragma unroll 1
        for (int t = 0; t < 11; ++t) {
            // prefetch row t+1 (+ its class constants) before the chain
            int roff = (start + swave + 4 * (t + 1)) * H;   // scalar
            const float2* rp = (const float2*)(x + roff);
            float2 na  = rp[lane];
            float2 nbb = (lane < 51) ? rp[64 + lane] : make_float2(0.f, 0.f);
            int nc = __builtin_amdgcn_readfirstlane(
                         label_index[start + swave + 4 * (t + 1)]);
            float nk0 = cls[nc],        nk1 = cls[NC + nc];
            float np0 = cls[2*NC + nc], np1 = cls[3*NC + nc];

            // body on current row
            float t0 = fast_tanh(a.x),  t1 = fast_tanh(a.y);
            float t2 = fast_tanh(bb.x), t3 = fast_tanh(bb.y);
            float d0 = w0a.x * t0 + w0a.y * t1 + w0b.x * t2 + w0b.y * t3;
            float d1 = w1a.x * t0 + w1a.y * t1 + w1b.x * t2 + w1b.y * t3;
#pragma unroll
            for (int m = 32; m; m >>= 1) {
                d0 += __shfl_xor(d0, m);
                d1 += __shfl_xor(d1, m);
            }
            float e0 = __expf(d0 + k0);
            float e1 = __expf(d1 + k1);
            z0 += e0; z1 += e1; sv0 += p0; sv1 += p1;
            acc0a.x = fmaf(e0, a.x,  acc0a.x); acc0a.y = fmaf(e0, a.y,  acc0a.y);
            acc0b.x = fmaf(e0, bb.x, acc0b.x); acc0b.y = fmaf(e0, bb.y, acc0b.y);
            acc1a.x = fmaf(e1, a.x,  acc1a.x); acc1a.y = fmaf(e1, a.y,  acc1a.y);
            acc1b.x = fmaf(e1, bb.x, acc1b.x); acc1b.y = fmaf(e1, bb.y, acc1b.y);

            // rotate
            a = na; bb = nbb; k0 = nk0; k1 = nk1; p0 = np0; p1 = np1;
        }
        // final row (no prefetch)
        {
            float t0 = fast_tanh(a.x),  t1 = fast_tanh(a.y);
            float t2 = fast_tanh(bb.x), t3 = fast_tanh(bb.y);
            float d0 = w0a.x * t0 + w0a.y * t1 + w0b.x * t2 + w0b.y * t3;
            float d1 = w1a.x * t0 + w1a.y * t1 + w1b.x * t2 + w1b.y * t3;
#pragma unroll
            for (int m = 32; m; m >>= 1) {
                d0 += __shfl_xor(d0, m);
                d1 += __shfl_xor(d1, m);
            }
            float e0 = __expf(d0 + k0);
            float e1 = __expf(d1 + k1);
            z0 += e0; z1 += e1; sv0 += p0; sv1 += p1;
            acc0a.x = fmaf(e0, a.x,  acc0a.x); acc0a.y = fmaf(e0, a.y,  acc0a.y);
            acc0b.x = fmaf(e0, bb.x, acc0b.x); acc0b.y = fmaf(e0, bb.y, acc0b.y);
            acc1a.x = fmaf(e1, a.x,  acc1a.x); acc1a.y = fmaf(e1, a.y,  acc1a.y);
            acc1b.x = fmaf(e1, bb.x, acc1b.x); acc1b.y = fmaf(e1, bb.y, acc1b.y);
        }
    } else {
        // Generic fallback (never taken for this problem's shapes).
        for (int i = swave; i < cnt; i += 4) {
            const float2* r2 = (const float2*)(x + (start + i) * H);
            float2 a = r2[lane];
            float2 bb = (lane < 51) ? r2[64 + lane] : make_float2(0.f, 0.f);
            float t0 = fast_tanh(a.x), t1 = fast_tanh(a.y);
            float t2 = fast_tanh(bb.x), t3 = fast_tanh(bb.y);
            float d0 = w0a.x * t0 + w0a.y * t1 + w0b.x * t2 + w0b.y * t3;
            float d1 = w1a.x * t0 + w1a.y * t1 + w1b.x * t2 + w1b.y * t3;
#pragma unroll
            for (int m = 32; m; m >>= 1) {
                d0 += __shfl_xor(d0, m);
                d1 += __shfl_xor(d1, m);
            }
            int c = __builtin_amdgcn_readfirstlane(label_index[start + i]);
            float e0 = __expf(d0 + cls[c]);
            float e1 = __expf(d1 + cls[NC + c]);
            z0 += e0; z1 += e1;
            sv0 += cls[2 * NC + c];
            sv1 += cls[3 * NC + c];
            acc0a.x = fmaf(e0, a.x,  acc0a.x); acc0a.y = fmaf(e0, a.y,  acc0a.y);
            acc0b.x = fmaf(e0, bb.x, acc0b.x); acc0b.y = fmaf(e0, bb.y, acc0b.y);
            acc1a.x = fmaf(e1, a.x,  acc1a.x); acc1a.y = fmaf(e1, a.y,  acc1a.y);
            acc1b.x = fmaf(e1, bb.x, acc1b.x); acc1b.y = fmaf(e1, bb.y, acc1b.y);
        }
    }

    // ---- Cross-wave merge through LDS (float2 stores, 2-way = free).
    float2* pw = (float2*)part[wave];
    pw[lane]       = acc0a;              // floats [0,128)
    pw[115 + lane] = acc1a;              // floats [230,358)
    if (lane < 51) {
        pw[64 + lane]       = acc0b;     // floats [128,230)
        pw[115 + 64 + lane] = acc1b;     // floats [358,460)
    }
    if (lane == 0) {
        zs[wave][0] = z0; zs[wave][1] = z1;
        zs[wave][2] = sv0; zs[wave][3] = sv1;
    }
    __syncthreads();

    float zt0 = zs[0][0] + zs[1][0] + zs[2][0] + zs[3][0];
    float zt1 = zs[0][1] + zs[1][1] + zs[2][1] + zs[3][1];
    float st0 = zs[0][2] + zs[1][2] + zs[2][2] + zs[3][2];
    float st1 = zs[0][3] + zs[1][3] + zs[2][3] + zs[3][3];
    float rc  = __builtin_amdgcn_rcpf((float)cnt);
    float s0  = st0 * rc * __builtin_amdgcn_rcpf(zt0);  // layer_att0 / z0
    float s1  = st1 * rc * __builtin_amdgcn_rcpf(zt1);  // layer_att1 / z1

    for (int t = tid; t < 2 * H; t += 256) {
        float s = part[0][t] + part[1][t] + part[2][t] + part[3][t];
        t01[t] = s * (t < H ? s0 : s1);
    }
    __syncthreads();

    // ---- Output projection, float4 both sides. 4 threads per class.
    int q = tid & 3;
    int c = tid >> 2;
    if (c < NC) {
        const float4* drow4 = (const float4*)(disc + c * (2 * H)); // 115 float4
        const float4* t4 = (const float4*)t01;
        float acc = 0.f;
        for (int k = q; k < 115; k += 4) {
            float4 dv = drow4[k];
            float4 tv = t4[k];
            acc += dv.x * tv.x + dv.y * tv.y + dv.z * tv.z + dv.w * tv.w;
        }
        acc += __shfl_down(acc, 2, 4);
        acc += __shfl_down(acc, 1, 4);
        if (q == 0) out[b * NC + c] = acc + bias[c];
    }
}

extern "C" void kernel_launch(void* const* d_in, const int* in_sizes, int n_in,
                              void* d_out, int out_size, void* d_ws, size_t ws_size,
                              hipStream_t stream) {
    const float* x               = (const float*)d_in[0];
    const float* rel_emb0        = (const float*)d_in[1];
    const float* rel_emb1        = (const float*)d_in[2];
    const float* att_w0          = (const float*)d_in[3];
    const float* att_w1          = (const float*)d_in[4];
    const float* w_s             = (const float*)d_in[5];
    const float* b_s             = (const float*)d_in[6];
    const float* disc            = (const float*)d_in[7];
    const float* bias            = (const float*)d_in[8];
    const int*   label_index     = (const int*)d_in[9];
    const int*   relation_levels = (const int*)d_in[10];
    const int*   scope           = (const int*)d_in[11];
    float* out = (float*)d_out;
    float* cls = (float*)d_ws;   // 4*NC floats

    class_table_kernel<<<NC, 64, 0, stream>>>(rel_emb0, rel_emb1, att_w0, att_w1,
                                              w_s, b_s, relation_levels, cls);
    bag_kernel<<<BAGS, 256, 0, stream>>>(x, w_s, disc, bias, label_index, scope,
                                         cls, out);
}